// Round 1
// baseline (6677.008 us; speedup 1.0000x reference)
//
#include <hip/hip_runtime.h>

#define S_LEN 1024
#define BATCH 64
#define I_DIM 256
#define H_DIM 512
#define NCL 4      // clusters (16 batch rows each)
#define NRK 32     // WGs per cluster (16 feats each)
#define ROWS 16
#define FPW 16
#define HSTR 520   // LDS row stride (bf16 elems) for h: 16B-aligned rows

typedef short short8 __attribute__((ext_vector_type(8)));
typedef float floatx4 __attribute__((ext_vector_type(4)));
typedef unsigned short ushortx4 __attribute__((ext_vector_type(4)));

__device__ inline unsigned short f2bf(float x){
  unsigned u = __float_as_uint(x);
  u += 0x7fffu + ((u >> 16) & 1u);           // RNE
  return (unsigned short)(u >> 16);
}
__device__ inline float bf2f(unsigned short s){
  return __uint_as_float(((unsigned)s) << 16);
}
__device__ inline float fast_tanh(float x){
  float e = __expf(2.0f * x);                // inf-safe: +inf -> 1, 0 -> -1
  return 1.0f - 2.0f / (e + 1.0f);
}
__device__ inline float fast_sigmoid(float x){
  return 1.0f / (1.0f + __expf(-x));
}
__device__ inline short8 cvt8(const float* p){
  short8 r;
#pragma unroll
  for (int j = 0; j < 8; j++) r[j] = (short)f2bf(p[j]);
  return r;
}

// ---------------------------------------------------------------------------
// Kernel P: A_in[t][F][b] = x[b,t,:]@W_in[F,:] + b_in[F]   (bf16)
//           A_tau[t][F][b] = x[b,t,:]@tau_w1[F,:256] + tau_b1[F]
// grid (1024 t, 8 fblocks), 256 thr. Wave w -> feats fb*64+w*16+(l&15).
// MFMA 16x16x32 bf16: A=x (m=b), B=W rows (n=feat), both frags contiguous-k.
// ---------------------------------------------------------------------------
__global__ __launch_bounds__(256) void precompute_kernel(
  const float* __restrict__ x, const float* __restrict__ W_in,
  const float* __restrict__ b_in, const float* __restrict__ tau_w1,
  const float* __restrict__ tau_b1,
  unsigned short* __restrict__ A_in, unsigned short* __restrict__ A_tau)
{
  const int t = blockIdx.x, fb = blockIdx.y;
  const int tid = threadIdx.x, w = tid >> 6;
  const int l15 = tid & 15, q = (tid & 63) >> 4;
  const int F = fb * 64 + w * 16 + l15;

  floatx4 accf[4], acct[4];
#pragma unroll
  for (int m = 0; m < 4; m++){ accf[m] = (floatx4){0,0,0,0}; acct[m] = (floatx4){0,0,0,0}; }

#pragma unroll
  for (int kc = 0; kc < 8; kc++){
    const int k0 = kc * 32 + q * 8;
    short8 bw = cvt8(&W_in[(size_t)F * I_DIM + k0]);
    short8 bt = cvt8(&tau_w1[(size_t)F * (I_DIM + H_DIM) + k0]);
#pragma unroll
    for (int m = 0; m < 4; m++){
      const int b = m * 16 + l15;
      short8 a = cvt8(&x[((size_t)b * S_LEN + t) * I_DIM + k0]);
      accf[m] = __builtin_amdgcn_mfma_f32_16x16x32_bf16(a, bw, accf[m], 0, 0, 0);
      acct[m] = __builtin_amdgcn_mfma_f32_16x16x32_bf16(a, bt, acct[m], 0, 0, 0);
    }
  }
  const float bi = b_in[F], bt1 = tau_b1[F];
  // D: col = lane&15 -> F ; row = q*4+i -> b = m*16+q*4+i. Pack 4 rows -> 8B store.
#pragma unroll
  for (int m = 0; m < 4; m++){
    ushortx4 pf, pt;
#pragma unroll
    for (int i2 = 0; i2 < 4; i2++){ pf[i2] = f2bf(accf[m][i2] + bi); pt[i2] = f2bf(acct[m][i2] + bt1); }
    const size_t base = ((size_t)t * H_DIM + F) * BATCH + m * 16 + q * 4;
    *(ushortx4*)(A_in + base) = pf;
    *(ushortx4*)(A_tau + base) = pt;
  }
}

// ---------------------------------------------------------------------------
// Kernel S: persistent scan. 128 WGs x 256 thr.
//   cluster = bid&3 (rows [cl*16, cl*16+16)), rank = bid>>2 (feats [rank*16,+16))
//   Per step: MFMA slice (W frags in regs, h from LDS) -> tanh -> sc1 bcast
//   (f slice bf16 + tau-dot partial f32) -> 1 device-scope sync -> every WG
//   redundantly rebuilds full h (tau, h_pre, LN) for its 16 rows.
// ---------------------------------------------------------------------------
__global__ __launch_bounds__(256) void scan_kernel(
  const float* __restrict__ h0, const float* __restrict__ W_rec,
  const float* __restrict__ tau_w1, const float* __restrict__ tau_w2,
  const float* __restrict__ tau_b2_p, const float* __restrict__ gamma,
  const float* __restrict__ beta,
  const unsigned short* __restrict__ A_in, const unsigned short* __restrict__ A_tau,
  unsigned short* __restrict__ bc_f, float* __restrict__ bc_td,
  unsigned int* __restrict__ counters,
  float* __restrict__ out0, float* __restrict__ outh, float* __restrict__ outtau)
{
  __shared__ unsigned short hB[ROWS * HSTR];   // 16.6 KB  h (bf16), padded rows
  __shared__ float redf[4 * 64 * 9];           // 9.2 KB   cross-wave partials (+1 pad)

  const int tid = threadIdx.x;
  const int cl   = blockIdx.x & (NCL - 1);
  const int rank = blockIdx.x >> 2;
  const int w = tid >> 6, l64 = tid & 63, l15 = tid & 15, q = (tid & 63) >> 4;
  const int F0 = rank * FPW;
  const int i_id = tid >> 6;                       // producer-epilogue: reg idx
  const int rb = ((l64 >> 4) << 2) + i_id;         // producer row (D-layout)
  const int fl = l64 & 15;                         // producer feat within slice
  const int rr = tid >> 4;                         // consumer row 0..15
  const int cc = tid & 15;                         // consumer 32-feat chunk

  // ---- init: weight fragments -> registers (reused 1024 steps) ----
  short8 wr[4], wt[4];
#pragma unroll
  for (int c = 0; c < 4; c++){
    const int k = w * 128 + c * 32 + q * 8;
    wr[c] = cvt8(&W_rec[(size_t)(F0 + l15) * H_DIM + k]);
    wt[c] = cvt8(&tau_w1[(size_t)(F0 + l15) * (I_DIM + H_DIM) + I_DIM + k]);
  }
  float h_reg[32], gamr[32], betr[32];
  {
    const int b = cl * ROWS + rr;
#pragma unroll
    for (int j = 0; j < 32; j++){
      float hv = h0[(size_t)b * H_DIM + cc * 32 + j];
      h_reg[j] = hv;
      hB[rr * HSTR + cc * 32 + j] = f2bf(hv);
      gamr[j] = gamma[cc * 32 + j];
      betr[j] = beta[cc * 32 + j];
    }
  }
  const float tw2v = tau_w2[F0 + fl];
  const float tb2 = tau_b2_p[0];
  __syncthreads();

  for (int t = 0; t < S_LEN; t++){
    // prefetch precomputed A terms (producer identity)
    const size_t aidx = ((size_t)t * H_DIM + (F0 + fl)) * BATCH + cl * ROWS + rb;
    const float a_f = bf2f(A_in[aidx]);
    const float a_t = bf2f(A_tau[aidx]);

    // matvec: wave w covers k quarter [w*128, w*128+128)
    floatx4 af = {0,0,0,0}, at4 = {0,0,0,0};
#pragma unroll
    for (int c = 0; c < 4; c++){
      short8 ha = *(const short8*)&hB[l15 * HSTR + w * 128 + c * 32 + q * 8];
      af  = __builtin_amdgcn_mfma_f32_16x16x32_bf16(ha, wr[c], af,  0, 0, 0);
      at4 = __builtin_amdgcn_mfma_f32_16x16x32_bf16(ha, wt[c], at4, 0, 0, 0);
    }
    // cross-wave K reduction via LDS (stride-9 pad -> 2-way max)
    const int rbase = w * 576 + l64 * 9;
#pragma unroll
    for (int i2 = 0; i2 < 4; i2++){ redf[rbase + i2] = af[i2]; redf[rbase + 4 + i2] = at4[i2]; }
    __syncthreads();
    float vf = a_f, vt = a_t;
#pragma unroll
    for (int w2 = 0; w2 < 4; w2++){
      vf += redf[w2 * 576 + l64 * 9 + i_id];
      vt += redf[w2 * 576 + l64 * 9 + 4 + i_id];
    }
    vf = fast_tanh(vf);          // f_xh slice value at (rb, F0+fl)
    vt = fast_tanh(vt);          // t_hid slice value

    const int par = t & 1;
    // broadcast f slice (pack bf16 pairs across fl,fl^1 -> u32 sc1 store)
    {
      unsigned pv = (unsigned)f2bf(vf);
      unsigned ov = (unsigned)__shfl_xor((int)pv, 1);
      if ((fl & 1) == 0){
        const size_t bcbase = ((size_t)(par * NCL + cl) * ROWS + rb) * H_DIM + F0 + fl;
        __hip_atomic_store((unsigned*)(bc_f + bcbase), pv | (ov << 16),
                           __ATOMIC_RELAXED, __HIP_MEMORY_SCOPE_AGENT);
      }
    }
    // tau-dot partial over this WG's 16 feats
    float pd = vt * tw2v;
    pd += __shfl_xor(pd, 1); pd += __shfl_xor(pd, 2);
    pd += __shfl_xor(pd, 4); pd += __shfl_xor(pd, 8);
    if (fl == 0)
      __hip_atomic_store(&bc_td[((size_t)(par * NCL + cl) * NRK + rank) * ROWS + rb], pd,
                         __ATOMIC_RELAXED, __HIP_MEMORY_SCOPE_AGENT);

    // make this thread's sc1 stores globally visible, then single arrive+poll
    __builtin_amdgcn_s_waitcnt(0);
    __syncthreads();
    if (tid == 0){
      __hip_atomic_fetch_add(&counters[cl], 1u, __ATOMIC_RELAXED, __HIP_MEMORY_SCOPE_AGENT);
      const unsigned tgt = (unsigned)(NRK * (t + 1));
      while (__hip_atomic_load(&counters[cl], __ATOMIC_ACQUIRE, __HIP_MEMORY_SCOPE_AGENT) < tgt)
        __builtin_amdgcn_s_sleep(2);
    }
    __syncthreads();

    // readback full f slice for (rr, feats cc*32..+32), device-scope loads
    float fv[32];
    const size_t fbase = ((size_t)(par * NCL + cl) * ROWS + rr) * H_DIM + cc * 32;
#pragma unroll
    for (int u = 0; u < 8; u++){
      unsigned long long v = __hip_atomic_load((const unsigned long long*)(bc_f + fbase + u * 4),
                                               __ATOMIC_RELAXED, __HIP_MEMORY_SCOPE_AGENT);
#pragma unroll
      for (int e = 0; e < 4; e++) fv[u * 4 + e] = bf2f((unsigned short)(v >> (16 * e)));
    }
    // tau: sum 32 rank-partials (2 per lane, then 16-lane xor tree)
    float td = __hip_atomic_load(&bc_td[((size_t)(par * NCL + cl) * NRK + cc) * ROWS + rr],
                                 __ATOMIC_RELAXED, __HIP_MEMORY_SCOPE_AGENT)
             + __hip_atomic_load(&bc_td[((size_t)(par * NCL + cl) * NRK + cc + 16) * ROWS + rr],
                                 __ATOMIC_RELAXED, __HIP_MEMORY_SCOPE_AGENT);
    td += __shfl_xor(td, 1); td += __shfl_xor(td, 2);
    td += __shfl_xor(td, 4); td += __shfl_xor(td, 8);
    const float tau = 1.0f + 9.0f * fast_sigmoid(td + tb2);
    const float c2 = 0.1f / tau, c1 = 1.0f - c2;

    // h_pre + LN (stats over 512 = 32/thread + 16-lane tree)
    float hp[32]; float s1 = 0.f, s2 = 0.f;
#pragma unroll
    for (int j = 0; j < 32; j++){
      float v2 = c1 * h_reg[j] + c2 * fv[j];
      hp[j] = v2; s1 += v2; s2 += v2 * v2;
    }
    s1 += __shfl_xor(s1, 1); s2 += __shfl_xor(s2, 1);
    s1 += __shfl_xor(s1, 2); s2 += __shfl_xor(s2, 2);
    s1 += __shfl_xor(s1, 4); s2 += __shfl_xor(s2, 4);
    s1 += __shfl_xor(s1, 8); s2 += __shfl_xor(s2, 8);
    const float mu = s1 * (1.0f / 512.0f);
    const float var = s2 * (1.0f / 512.0f) - mu * mu;
    const float rs = rsqrtf(var + 1e-5f);
#pragma unroll
    for (int j = 0; j < 32; j++) h_reg[j] = (hp[j] - mu) * rs * gamr[j] + betr[j];

    // h -> LDS bf16 for next matvec
#pragma unroll
    for (int u = 0; u < 4; u++){
      short8 hv;
#pragma unroll
      for (int e = 0; e < 8; e++) hv[e] = (short)f2bf(h_reg[u * 8 + e]);
      *(short8*)&hB[rr * HSTR + cc * 32 + u * 8] = hv;
    }
    // outputs: this rank writes its 16-feat window of output[b][t][:]
    if (cc == (rank >> 1)){
      const int j0 = (rank & 1) * 16;
      float* dst = out0 + ((size_t)(cl * ROWS + rr) * S_LEN + t) * H_DIM + rank * FPW;
#pragma unroll
      for (int j2 = 0; j2 < 16; j2++) dst[j2] = h_reg[j0 + j2];
    }
    if (rank == 0 && cc == 0) outtau[(size_t)(cl * ROWS + rr) * S_LEN + t] = tau;
    if (t == S_LEN - 1 && rank == 0){
#pragma unroll
      for (int j = 0; j < 32; j++)
        outh[(size_t)(cl * ROWS + rr) * H_DIM + cc * 32 + j] = h_reg[j];
    }
    __syncthreads();
  }
}

extern "C" void kernel_launch(void* const* d_in, const int* in_sizes, int n_in,
                              void* d_out, int out_size, void* d_ws, size_t ws_size,
                              hipStream_t stream) {
  const float* x      = (const float*)d_in[0];
  const float* h0     = (const float*)d_in[1];
  const float* W_in   = (const float*)d_in[2];
  const float* b_in   = (const float*)d_in[3];
  const float* W_rec  = (const float*)d_in[4];
  const float* tau_w1 = (const float*)d_in[5];
  const float* tau_b1 = (const float*)d_in[6];
  const float* tau_w2 = (const float*)d_in[7];
  const float* tau_b2 = (const float*)d_in[8];
  const float* gamma  = (const float*)d_in[9];
  const float* beta   = (const float*)d_in[10];

  char* ws = (char*)d_ws;
  unsigned short* A_in   = (unsigned short*)(ws);                 // 67,108,864 B
  unsigned short* A_tau  = (unsigned short*)(ws + 67108864);      // 67,108,864 B
  unsigned short* bc_f   = (unsigned short*)(ws + 134217728);     // 131,072 B
  float*          bc_td  = (float*)(ws + 134348800);              // 16,384 B
  unsigned int*   counters = (unsigned int*)(ws + 134365184);     // 256 B

  float* out0   = (float*)d_out;
  float* outh   = out0 + (size_t)BATCH * S_LEN * H_DIM;           // 33,554,432
  float* outtau = outh + (size_t)BATCH * H_DIM;                   // +32,768

  hipMemsetAsync(counters, 0, 256, stream);
  precompute_kernel<<<dim3(S_LEN, 8), 256, 0, stream>>>(x, W_in, b_in, tau_w1, tau_b1, A_in, A_tau);
  scan_kernel<<<dim3(NCL * NRK), 256, 0, stream>>>(h0, W_rec, tau_w1, tau_w2, tau_b2, gamma, beta,
                                                   A_in, A_tau, bc_f, bc_td, counters,
                                                   out0, outh, outtau);
}

// Round 2
// 4454.686 us; speedup vs baseline: 1.4989x; 1.4989x over previous
//
#include <hip/hip_runtime.h>

#define S_LEN 1024
#define BATCH 64
#define I_DIM 256
#define H_DIM 512
#define NCL 4      // clusters (16 batch rows each)
#define NRK 32     // WGs per cluster (16 feats each)
#define ROWS 16
#define FPW 16
#define HSTR 520   // LDS row stride (bf16 elems) for h: 16B-aligned rows
#define XSTR 264   // LDS row stride (bf16) for x staging in precompute

typedef short short8 __attribute__((ext_vector_type(8)));
typedef float floatx4 __attribute__((ext_vector_type(4)));
typedef unsigned short ushortx4 __attribute__((ext_vector_type(4)));

__device__ inline unsigned short f2bf(float x){
  unsigned u = __float_as_uint(x);
  u += 0x7fffu + ((u >> 16) & 1u);           // RNE
  return (unsigned short)(u >> 16);
}
__device__ inline float bf2f(unsigned short s){
  return __uint_as_float(((unsigned)s) << 16);
}
__device__ inline float fast_tanh(float x){
  float e = __expf(2.0f * x);                // inf-safe: +inf -> 1, 0 -> -1
  return 1.0f - 2.0f / (e + 1.0f);
}
__device__ inline float fast_sigmoid(float x){
  return 1.0f / (1.0f + __expf(-x));
}
__device__ inline short8 cvt8(const float* p){
  short8 r;
#pragma unroll
  for (int j = 0; j < 8; j++) r[j] = (short)f2bf(p[j]);
  return r;
}

// ---------------------------------------------------------------------------
// Kernel W: pre-convert W_in and tau_w1[:, :256] to bf16 (removes per-block
// f32->bf16 VALU work in precompute). grid 512 (feat), 256 thr (k).
// ---------------------------------------------------------------------------
__global__ __launch_bounds__(256) void convert_weights_kernel(
  const float* __restrict__ W_in, const float* __restrict__ tau_w1,
  unsigned short* __restrict__ Wbf, unsigned short* __restrict__ Tbf)
{
  const int f = blockIdx.x, k = threadIdx.x;
  Wbf[f * I_DIM + k] = f2bf(W_in[(size_t)f * I_DIM + k]);
  Tbf[f * I_DIM + k] = f2bf(tau_w1[(size_t)f * (I_DIM + H_DIM) + k]);
}

// ---------------------------------------------------------------------------
// Kernel P: A_in[t][F][b] = x[b,t,:]@W_in[F,:] + b_in[F]   (bf16)
//           A_tau[t][F][b] = x[b,t,:]@tau_w1[F,:256] + tau_b1[F]
// grid 1024 (t), 256 thr. Stage x[.,t,:] -> LDS bf16 ONCE, loop 8 fblocks.
// MFMA 16x16x32 bf16; D layout col=lane&15 (feat), row=q*4+i (batch) [m89].
// ---------------------------------------------------------------------------
__global__ __launch_bounds__(256) void precompute_kernel(
  const float* __restrict__ x, const unsigned short* __restrict__ Wbf,
  const unsigned short* __restrict__ Tbf,
  const float* __restrict__ b_in, const float* __restrict__ tau_b1,
  unsigned short* __restrict__ A_in, unsigned short* __restrict__ A_tau)
{
  __shared__ unsigned short xs[BATCH * XSTR];   // 33.8 KB, 2-way max conflicts
  const int t = blockIdx.x, tid = threadIdx.x;

  // stage: 4 threads per batch row, 64 consecutive f32 each
  {
    const int br = tid >> 2, pp = tid & 3;
    const float* xrow = x + ((size_t)br * S_LEN + t) * I_DIM + pp * 64;
    unsigned short* drow = xs + br * XSTR + pp * 64;
#pragma unroll
    for (int c = 0; c < 16; c++){
      float4 v = *(const float4*)(xrow + c * 4);
      ushortx4 o; o[0] = f2bf(v.x); o[1] = f2bf(v.y); o[2] = f2bf(v.z); o[3] = f2bf(v.w);
      *(ushortx4*)(drow + c * 4) = o;
    }
  }
  __syncthreads();

  const int w = tid >> 6, l15 = tid & 15, q = (tid & 63) >> 4;
#pragma unroll 1
  for (int fb = 0; fb < 8; fb++){
    const int F = fb * 64 + w * 16 + l15;
    floatx4 accf[4], acct[4];
#pragma unroll
    for (int m = 0; m < 4; m++){ accf[m] = (floatx4){0,0,0,0}; acct[m] = (floatx4){0,0,0,0}; }
#pragma unroll
    for (int kc = 0; kc < 8; kc++){
      const int k0 = kc * 32 + q * 8;
      short8 bw = *(const short8*)&Wbf[F * I_DIM + k0];
      short8 bt = *(const short8*)&Tbf[F * I_DIM + k0];
#pragma unroll
      for (int m = 0; m < 4; m++){
        short8 a = *(const short8*)&xs[(m * 16 + l15) * XSTR + k0];
        accf[m] = __builtin_amdgcn_mfma_f32_16x16x32_bf16(a, bw, accf[m], 0, 0, 0);
        acct[m] = __builtin_amdgcn_mfma_f32_16x16x32_bf16(a, bt, acct[m], 0, 0, 0);
      }
    }
    const float bi = b_in[F], bt1 = tau_b1[F];
#pragma unroll
    for (int m = 0; m < 4; m++){
      ushortx4 pf, pt;
#pragma unroll
      for (int i2 = 0; i2 < 4; i2++){ pf[i2] = f2bf(accf[m][i2] + bi); pt[i2] = f2bf(acct[m][i2] + bt1); }
      const size_t base = ((size_t)t * H_DIM + F) * BATCH + m * 16 + q * 4;
      *(ushortx4*)(A_in + base) = pf;
      *(ushortx4*)(A_tau + base) = pt;
    }
  }
}

// ---------------------------------------------------------------------------
// Kernel S: persistent scan. 128 WGs x 256 thr.
//   Per step: MFMA slice (W frags in regs, h from LDS) -> tanh -> sc1 bcast
//   -> per-rank stamped flag (store-only barrier, RELAXED agent polling;
//   no acquire => no L2 invalidate thrash) -> every WG redundantly rebuilds
//   full h (tau, h_pre, LN) for its 16 rows.
// ---------------------------------------------------------------------------
__global__ __launch_bounds__(256) void scan_kernel(
  const float* __restrict__ h0, const float* __restrict__ W_rec,
  const float* __restrict__ tau_w1, const float* __restrict__ tau_w2,
  const float* __restrict__ tau_b2_p, const float* __restrict__ gamma,
  const float* __restrict__ beta,
  const unsigned short* __restrict__ A_in, const unsigned short* __restrict__ A_tau,
  unsigned short* __restrict__ bc_f, float* __restrict__ bc_td,
  unsigned int* __restrict__ flags,
  float* __restrict__ out0, float* __restrict__ outh, float* __restrict__ outtau)
{
  __shared__ unsigned short hB[ROWS * HSTR];   // 16.6 KB  h (bf16), padded rows
  __shared__ float redf[4 * 64 * 9];           // 9.2 KB   cross-wave partials (+1 pad)

  const int tid = threadIdx.x;
  const int cl   = blockIdx.x & (NCL - 1);
  const int rank = blockIdx.x >> 2;
  const int w = tid >> 6, l64 = tid & 63, l15 = tid & 15, q = (tid & 63) >> 4;
  const int F0 = rank * FPW;
  const int i_id = tid >> 6;                       // producer-epilogue: reg idx
  const int rb = ((l64 >> 4) << 2) + i_id;         // producer row (D-layout)
  const int fl = l64 & 15;                         // producer feat within slice
  const int rr = tid >> 4;                         // consumer row 0..15
  const int cc = tid & 15;                         // consumer 32-feat chunk

  // ---- init: weight fragments -> registers (reused 1024 steps) ----
  short8 wr[4], wt[4];
#pragma unroll
  for (int c = 0; c < 4; c++){
    const int k = w * 128 + c * 32 + q * 8;
    wr[c] = cvt8(&W_rec[(size_t)(F0 + l15) * H_DIM + k]);
    wt[c] = cvt8(&tau_w1[(size_t)(F0 + l15) * (I_DIM + H_DIM) + I_DIM + k]);
  }
  float h_reg[32], gamr[32], betr[32];
  {
    const int b = cl * ROWS + rr;
#pragma unroll
    for (int j = 0; j < 32; j++){
      float hv = h0[(size_t)b * H_DIM + cc * 32 + j];
      h_reg[j] = hv;
      hB[rr * HSTR + cc * 32 + j] = f2bf(hv);
      gamr[j] = gamma[cc * 32 + j];
      betr[j] = beta[cc * 32 + j];
    }
  }
  const float tw2v = tau_w2[F0 + fl];
  const float tb2 = tau_b2_p[0];

  // prefetch A terms for t=0 (raw bf16, converted at use)
  unsigned short af_raw, at_raw;
  {
    const size_t aidx = ((size_t)(F0 + fl)) * BATCH + cl * ROWS + rb;
    af_raw = A_in[aidx];
    at_raw = A_tau[aidx];
  }
  __syncthreads();

  for (int t = 0; t < S_LEN; t++){
    const float a_f = bf2f(af_raw);
    const float a_t = bf2f(at_raw);

    // matvec: wave w covers k quarter [w*128, w*128+128)
    floatx4 af = {0,0,0,0}, at4 = {0,0,0,0};
#pragma unroll
    for (int c = 0; c < 4; c++){
      short8 ha = *(const short8*)&hB[l15 * HSTR + w * 128 + c * 32 + q * 8];
      af  = __builtin_amdgcn_mfma_f32_16x16x32_bf16(ha, wr[c], af,  0, 0, 0);
      at4 = __builtin_amdgcn_mfma_f32_16x16x32_bf16(ha, wt[c], at4, 0, 0, 0);
    }
    // cross-wave K reduction via LDS (stride-9 pad)
    const int rbase = w * 576 + l64 * 9;
#pragma unroll
    for (int i2 = 0; i2 < 4; i2++){ redf[rbase + i2] = af[i2]; redf[rbase + 4 + i2] = at4[i2]; }
    __syncthreads();
    float vf = a_f, vt = a_t;
#pragma unroll
    for (int w2 = 0; w2 < 4; w2++){
      vf += redf[w2 * 576 + l64 * 9 + i_id];
      vt += redf[w2 * 576 + l64 * 9 + 4 + i_id];
    }
    vf = fast_tanh(vf);          // f_xh slice value at (rb, F0+fl)
    vt = fast_tanh(vt);          // t_hid slice value

    const int par = t & 1;
    // broadcast f slice (pack bf16 pairs across fl,fl^1 -> u32 sc1 store)
    {
      unsigned pv = (unsigned)f2bf(vf);
      unsigned ov = (unsigned)__shfl_xor((int)pv, 1);
      if ((fl & 1) == 0){
        const size_t bcbase = ((size_t)(par * NCL + cl) * ROWS + rb) * H_DIM + F0 + fl;
        __hip_atomic_store((unsigned*)(bc_f + bcbase), pv | (ov << 16),
                           __ATOMIC_RELAXED, __HIP_MEMORY_SCOPE_AGENT);
      }
    }
    // tau-dot partial over this WG's 16 feats
    float pd = vt * tw2v;
    pd += __shfl_xor(pd, 1); pd += __shfl_xor(pd, 2);
    pd += __shfl_xor(pd, 4); pd += __shfl_xor(pd, 8);
    if (fl == 0)
      __hip_atomic_store(&bc_td[((size_t)(par * NCL + cl) * NRK + rank) * ROWS + rb], pd,
                         __ATOMIC_RELAXED, __HIP_MEMORY_SCOPE_AGENT);

    // drain own sc1 stores, then store-only arrival flag (stamp = t+1)
    __builtin_amdgcn_s_waitcnt(0);
    __syncthreads();
    const int fbi = (par * NCL + cl) << 5;
    if (tid == 0)
      __hip_atomic_store(&flags[fbi | rank], (unsigned)(t + 1),
                         __ATOMIC_RELAXED, __HIP_MEMORY_SCOPE_AGENT);
    // prefetch A terms for t+1 — in flight during the poll wait
    if (t + 1 < S_LEN){
      const size_t aidx = ((size_t)(t + 1) * H_DIM + (F0 + fl)) * BATCH + cl * ROWS + rb;
      af_raw = A_in[aidx];
      at_raw = A_tau[aidx];
    }
    // wave 0: per-lane poll of all 32 rank flags (RELAXED sc1 — no L2 inv)
    if (w == 0){
      const unsigned tgt = (unsigned)(t + 1);
      while (__hip_atomic_load(&flags[fbi | (l64 & 31)],
                               __ATOMIC_RELAXED, __HIP_MEMORY_SCOPE_AGENT) < tgt)
        __builtin_amdgcn_s_sleep(1);
    }
    asm volatile("" ::: "memory");
    __syncthreads();

    // readback full f slice for (rr, feats cc*32..+32)
    float fv[32];
    const size_t fbase = ((size_t)(par * NCL + cl) * ROWS + rr) * H_DIM + cc * 32;
#pragma unroll
    for (int u = 0; u < 8; u++){
      unsigned long long v = __hip_atomic_load((const unsigned long long*)(bc_f + fbase + u * 4),
                                               __ATOMIC_RELAXED, __HIP_MEMORY_SCOPE_AGENT);
#pragma unroll
      for (int e = 0; e < 4; e++) fv[u * 4 + e] = bf2f((unsigned short)(v >> (16 * e)));
    }
    // tau: sum 32 rank-partials (2 per lane, then 16-lane xor tree)
    float td = __hip_atomic_load(&bc_td[((size_t)(par * NCL + cl) * NRK + cc) * ROWS + rr],
                                 __ATOMIC_RELAXED, __HIP_MEMORY_SCOPE_AGENT)
             + __hip_atomic_load(&bc_td[((size_t)(par * NCL + cl) * NRK + cc + 16) * ROWS + rr],
                                 __ATOMIC_RELAXED, __HIP_MEMORY_SCOPE_AGENT);
    td += __shfl_xor(td, 1); td += __shfl_xor(td, 2);
    td += __shfl_xor(td, 4); td += __shfl_xor(td, 8);
    const float tau = 1.0f + 9.0f * fast_sigmoid(td + tb2);
    const float c2 = 0.1f / tau, c1 = 1.0f - c2;

    // h_pre + LN (stats over 512 = 32/thread + 16-lane tree)
    float hp[32]; float s1 = 0.f, s2 = 0.f;
#pragma unroll
    for (int j = 0; j < 32; j++){
      float v2 = c1 * h_reg[j] + c2 * fv[j];
      hp[j] = v2; s1 += v2; s2 += v2 * v2;
    }
    s1 += __shfl_xor(s1, 1); s2 += __shfl_xor(s2, 1);
    s1 += __shfl_xor(s1, 2); s2 += __shfl_xor(s2, 2);
    s1 += __shfl_xor(s1, 4); s2 += __shfl_xor(s2, 4);
    s1 += __shfl_xor(s1, 8); s2 += __shfl_xor(s2, 8);
    const float mu = s1 * (1.0f / 512.0f);
    const float var = s2 * (1.0f / 512.0f) - mu * mu;
    const float rs = rsqrtf(var + 1e-5f);
#pragma unroll
    for (int j = 0; j < 32; j++) h_reg[j] = (hp[j] - mu) * rs * gamr[j] + betr[j];

    // h -> LDS bf16 for next matvec
#pragma unroll
    for (int u = 0; u < 4; u++){
      short8 hv;
#pragma unroll
      for (int e = 0; e < 8; e++) hv[e] = (short)f2bf(h_reg[u * 8 + e]);
      *(short8*)&hB[rr * HSTR + cc * 32 + u * 8] = hv;
    }
    // outputs: this rank writes its 16-feat window of output[b][t][:]
    if (cc == (rank >> 1)){
      const int j0 = (rank & 1) * 16;
      float* dst = out0 + ((size_t)(cl * ROWS + rr) * S_LEN + t) * H_DIM + rank * FPW;
#pragma unroll
      for (int j2 = 0; j2 < 16; j2++) dst[j2] = h_reg[j0 + j2];
    }
    if (rank == 0 && cc == 0) outtau[(size_t)(cl * ROWS + rr) * S_LEN + t] = tau;
    if (t == S_LEN - 1 && rank == 0){
#pragma unroll
      for (int j = 0; j < 32; j++)
        outh[(size_t)(cl * ROWS + rr) * H_DIM + cc * 32 + j] = h_reg[j];
    }
    __syncthreads();
  }
}

extern "C" void kernel_launch(void* const* d_in, const int* in_sizes, int n_in,
                              void* d_out, int out_size, void* d_ws, size_t ws_size,
                              hipStream_t stream) {
  const float* x      = (const float*)d_in[0];
  const float* h0     = (const float*)d_in[1];
  const float* W_in   = (const float*)d_in[2];
  const float* b_in   = (const float*)d_in[3];
  const float* W_rec  = (const float*)d_in[4];
  const float* tau_w1 = (const float*)d_in[5];
  const float* tau_b1 = (const float*)d_in[6];
  const float* tau_w2 = (const float*)d_in[7];
  const float* tau_b2 = (const float*)d_in[8];
  const float* gamma  = (const float*)d_in[9];
  const float* beta   = (const float*)d_in[10];

  char* ws = (char*)d_ws;
  unsigned short* A_in   = (unsigned short*)(ws);                 // 67,108,864 B
  unsigned short* A_tau  = (unsigned short*)(ws + 67108864);      // 67,108,864 B
  unsigned short* bc_f   = (unsigned short*)(ws + 134217728);     // 131,072 B
  float*          bc_td  = (float*)(ws + 134348800);              // 16,384 B
  unsigned int*   flags  = (unsigned int*)(ws + 134365184);       // 1,024 B
  unsigned short* Wbf    = (unsigned short*)(ws + 134366208);     // 262,144 B
  unsigned short* Tbf    = (unsigned short*)(ws + 134628352);     // 262,144 B

  float* out0   = (float*)d_out;
  float* outh   = out0 + (size_t)BATCH * S_LEN * H_DIM;           // 33,554,432
  float* outtau = outh + (size_t)BATCH * H_DIM;                   // +32,768

  hipMemsetAsync(flags, 0, 1024, stream);
  convert_weights_kernel<<<dim3(H_DIM), 256, 0, stream>>>(W_in, tau_w1, Wbf, Tbf);
  precompute_kernel<<<dim3(S_LEN), 256, 0, stream>>>(x, Wbf, Tbf, b_in, tau_b1, A_in, A_tau);
  scan_kernel<<<dim3(NCL * NRK), 256, 0, stream>>>(h0, W_rec, tau_w1, tau_w2, tau_b2, gamma, beta,
                                                   A_in, A_tau, bc_f, bc_td, flags,
                                                   out0, outh, outtau);
}